// Round 5
// baseline (304.748 us; speedup 1.0000x reference)
//
#include <hip/hip_runtime.h>
#include <hip/hip_bf16.h>
#include <stdint.h>

// Problem constants
#define NLAYERS 32
#define DSIZE   1024
#define OSIZE   1024
#define BATCH   32
#define SEQ     256

// ws layout: ints [0]=ntiles; [16..272)=perm; [512+4t..]=tile{layer,rank_base,nranks}
// bytes [65536 .. 65536+16MB) = x converted to bf16 (same [b,s,d] layout)
#define WS_PERM  16
#define WS_TILE  512
#define MAX_TILES 88   // sum ceil(cnt/4) <= 88
#define XBF_OFF  65536

typedef __attribute__((ext_vector_type(8)))  short short8;
typedef __attribute__((ext_vector_type(16))) float f32x16;

#define LDSTRIDE 72   // shorts per LDS row: stride 36 floats ≡ 4 (mod 32) -> b128 reads conflict-free
#define BK 64

__global__ void prep_kernel(const int* __restrict__ layer_idx, int* __restrict__ wsi) {
    __shared__ int cnt[NLAYERS];
    __shared__ int start_[NLAYERS];
    __shared__ int cursor[NLAYERS];
    const int t = threadIdx.x;
    if (t < NLAYERS) cnt[t] = 0;
    __syncthreads();
    int l = 0;
    if (t < SEQ) { l = layer_idx[t]; atomicAdd(&cnt[l], 1); }
    __syncthreads();
    if (t == 0) {
        int acc = 0;
        for (int i = 0; i < NLAYERS; ++i) { start_[i] = acc; cursor[i] = acc; acc += cnt[i]; }
    }
    __syncthreads();
    if (t < SEQ) {
        int r = atomicAdd(&cursor[l], 1);
        wsi[WS_PERM + r] = t;           // perm[rank] = s
    }
    if (t == 0) {
        int nt = 0;
        for (int i = 0; i < NLAYERS; ++i) {
            const int c = cnt[i];
            for (int j = 0; j < c; j += 4) {
                wsi[WS_TILE + nt*4 + 0] = i;
                wsi[WS_TILE + nt*4 + 1] = start_[i] + j;
                wsi[WS_TILE + nt*4 + 2] = (c - j < 4) ? (c - j) : 4;
                ++nt;
            }
        }
        wsi[0] = nt;
    }
}

// round-to-nearest fp32->bf16 pair pack: low16 = bf16(a), high16 = bf16(b)
static __device__ __forceinline__ unsigned pk2(float a, float b) {
    unsigned ua = __builtin_bit_cast(unsigned, a) + 0x8000u;
    unsigned ub = __builtin_bit_cast(unsigned, b) + 0x8000u;
    return __builtin_amdgcn_perm(ub, ua, 0x07060302u);
}

// streaming x fp32 -> bf16 (8 float4 per thread, 1024x256 grid covers 2^21 float4 exactly)
__global__ __launch_bounds__(256) void xconv_kernel(const float4* __restrict__ x4,
                                                    uint2* __restrict__ xb) {
    const int tid = blockIdx.x * 256 + threadIdx.x;
    const int NT  = 1024 * 256;
    #pragma unroll
    for (int i = 0; i < 8; ++i) {
        const int idx = tid + i * NT;
        float4 v = x4[idx];
        uint2 o;
        o.x = pk2(v.x, v.y);
        o.y = pk2(v.z, v.w);
        xb[idx] = o;
    }
}

// Tile: M=128 (4 ranks x 32 batch) x N=128, BK=64, 4 waves (2m x 2n of 64x64).
template<bool PREBF>
__global__ __launch_bounds__(256, 4) void gemm_kernel(
        const float* __restrict__ x, const unsigned short* __restrict__ xbf,
        const float* __restrict__ wgt, const int* __restrict__ wsi,
        float* __restrict__ out) {
    const int ntiles = wsi[0];
    const int mt = blockIdx.y;
    if (mt >= ntiles) return;
    const int layer     = wsi[WS_TILE + mt*4 + 0];
    const int rank_base = wsi[WS_TILE + mt*4 + 1];
    const int nranks    = wsi[WS_TILE + mt*4 + 2];
    const int ntile     = blockIdx.x;   // 0..7 -> o block of 128

    __shared__ __align__(16) short ldsA[128 * LDSTRIDE];
    __shared__ __align__(16) short ldsB[128 * LDSTRIDE];

    const int t = threadIdx.x;

    bool svalid[4];
    int  sv[4];
    #pragma unroll
    for (int j = 0; j < 4; ++j) {
        svalid[j] = (j < nranks);
        sv[j] = svalid[j] ? wsi[WS_PERM + rank_base + j] : 0;
    }

    // ---- B staging (fp32): 8 passes, wave = 4 rows x 16 lanes x 16B
    const int c4     = (t & 15) * 4;   // float col within 64-wide k-slab (== short col)
    const int rbaseB = t >> 4;         // 0..15; pass p -> row rbaseB + 16p
    const float* bbase = wgt + (((size_t)((layer << 10) + ntile * 128 + rbaseB)) << 10) + c4;

    // ---- A staging
    // PREBF: bf16 16B/lane: c8=(t&7)*8 shorts, rbaseA8 = t>>3 (=batch), pass p -> row 32p+rbaseA8 (rank p)
    const int c8      = (t & 7) * 8;
    const int rbaseA8 = t >> 3;        // 0..31
    const unsigned short* aptr8[4];
    #pragma unroll
    for (int p = 0; p < 4; ++p)
        aptr8[p] = xbf + (((size_t)(rbaseA8 * SEQ + sv[p])) << 10) + c8;
    // !PREBF: fp32: rows rbaseA4 + 16p, rank = p>>1, batch = rbaseA4 + 16(p&1)
    const int rbaseA4 = t >> 4;
    const float* aptr4[8];
    #pragma unroll
    for (int p = 0; p < 8; ++p) {
        const int b = rbaseA4 + ((p & 1) << 4);
        aptr4[p] = x + (((size_t)(b * SEQ + sv[p >> 1])) << 10) + c4;
    }

    short8 ra16[4];
    float4 ra32[8];
    float4 rb[8];
    auto load_step = [&](int kk) {
        if (PREBF) {
            #pragma unroll
            for (int p = 0; p < 4; ++p) {
                if (svalid[p]) ra16[p] = *(const short8*)(aptr8[p] + kk);
                else           ra16[p] = short8{0,0,0,0,0,0,0,0};
            }
        } else {
            #pragma unroll
            for (int p = 0; p < 8; ++p) {
                if (svalid[p >> 1]) ra32[p] = *(const float4*)(aptr4[p] + kk);
                else                ra32[p] = make_float4(0.f, 0.f, 0.f, 0.f);
            }
        }
        #pragma unroll
        for (int p = 0; p < 8; ++p)
            rb[p] = *(const float4*)(bbase + ((size_t)(16 * p) << 10) + kk);
    };

    // compute-side mapping: 4 waves = 2m x 2n of 64x64
    const int lane = t & 63;
    const int wv   = t >> 6;
    const int wm   = (wv & 1) * 64;
    const int wn   = (wv >> 1) * 64;
    const int l31  = lane & 31;
    const int lh   = lane >> 5;

    f32x16 acc[2][2];
    #pragma unroll
    for (int mi = 0; mi < 2; ++mi)
        #pragma unroll
        for (int ni = 0; ni < 2; ++ni)
            #pragma unroll
            for (int r = 0; r < 16; ++r) acc[mi][ni][r] = 0.f;

    const short* pA0 = &ldsA[(wm + l31) * LDSTRIDE + lh * 8];
    const short* pB0 = &ldsB[(wn + l31) * LDSTRIDE + lh * 8];

    load_step(0);
    #pragma unroll 1
    for (int kk = 0; kk < DSIZE; kk += BK) {
        __syncthreads();   // previous compute done reading LDS
        if (PREBF) {
            #pragma unroll
            for (int p = 0; p < 4; ++p) {
                const int row = rbaseA8 + 32 * p;
                *(short8*)&ldsA[row * LDSTRIDE + c8] = ra16[p];
            }
        } else {
            #pragma unroll
            for (int p = 0; p < 8; ++p) {
                const int row = rbaseA4 + 16 * p;
                uint2 va;
                va.x = pk2(ra32[p].x, ra32[p].y);
                va.y = pk2(ra32[p].z, ra32[p].w);
                *(uint2*)&ldsA[row * LDSTRIDE + c4] = va;
            }
        }
        #pragma unroll
        for (int p = 0; p < 8; ++p) {
            const int row = rbaseB + 16 * p;
            uint2 vb;
            vb.x = pk2(rb[p].x, rb[p].y);
            vb.y = pk2(rb[p].z, rb[p].w);
            *(uint2*)&ldsB[row * LDSTRIDE + c4] = vb;
        }
        __syncthreads();
        if (kk + BK < DSIZE) load_step(kk + BK);  // prefetch overlaps MFMA below
        #pragma unroll
        for (int sub = 0; sub < 4; ++sub) {       // 4 x (K=16) sub-steps
            short8 a0 = *(const short8*)(pA0 + sub*16);
            short8 a1 = *(const short8*)(pA0 + 32*LDSTRIDE + sub*16);
            short8 b0 = *(const short8*)(pB0 + sub*16);
            short8 b1 = *(const short8*)(pB0 + 32*LDSTRIDE + sub*16);
            acc[0][0] = __builtin_amdgcn_mfma_f32_32x32x16_bf16(a0, b0, acc[0][0], 0, 0, 0);
            acc[0][1] = __builtin_amdgcn_mfma_f32_32x32x16_bf16(a0, b1, acc[0][1], 0, 0, 0);
            acc[1][0] = __builtin_amdgcn_mfma_f32_32x32x16_bf16(a1, b0, acc[1][0], 0, 0, 0);
            acc[1][1] = __builtin_amdgcn_mfma_f32_32x32x16_bf16(a1, b1, acc[1][1], 0, 0, 0);
        }
    }

    // epilogue: C/D layout col = lane&31, row = (reg&3) + 8*(reg>>2) + 4*(lane>>5)
    #pragma unroll
    for (int mi = 0; mi < 2; ++mi) {
        const int roff = (wv & 1) * 2 + mi;
        if (roff >= nranks) continue;
        const int s = sv[roff];
        #pragma unroll
        for (int ni = 0; ni < 2; ++ni) {
            const int ocol = ntile * 128 + wn + ni * 32 + l31;
            #pragma unroll
            for (int r = 0; r < 16; ++r) {
                const int brow = (r & 3) + 8 * (r >> 2) + 4 * lh;  // = batch b
                out[(((size_t)(brow * SEQ + s)) << 10) + ocol] = acc[mi][ni][r];
            }
        }
    }
}

extern "C" void kernel_launch(void* const* d_in, const int* in_sizes, int n_in,
                              void* d_out, int out_size, void* d_ws, size_t ws_size,
                              hipStream_t stream) {
    const float* x         = (const float*)d_in[0];
    const int*   layer_idx = (const int*)  d_in[1];
    const float* weight    = (const float*)d_in[2];
    float* out = (float*)d_out;
    int*   wsi = (int*)d_ws;
    unsigned short* xbf = (unsigned short*)((char*)d_ws + XBF_OFF);

    const bool prebf = ws_size >= (size_t)XBF_OFF + ((size_t)1 << 24);  // 16 MB bf16 mirror

    if (prebf)
        xconv_kernel<<<1024, 256, 0, stream>>>((const float4*)x, (uint2*)xbf);
    prep_kernel<<<1, 256, 0, stream>>>(layer_idx, wsi);
    if (prebf)
        gemm_kernel<true ><<<dim3(8, MAX_TILES), 256, 0, stream>>>(x, xbf, weight, wsi, out);
    else
        gemm_kernel<false><<<dim3(8, MAX_TILES), 256, 0, stream>>>(x, xbf, weight, wsi, out);
}